// Round 2
// baseline (436.360 us; speedup 1.0000x reference)
//
#include <hip/hip_runtime.h>
#include <hip/hip_bf16.h>

#define N 4096
#define IN_DIM 256
#define HID 64
#define NHEADS 4
#define OUT_DIM 128
#define LOG2E 1.44269504088896340736f
#define NBLK 512

typedef __attribute__((ext_vector_type(8))) short bf16x8;
typedef __attribute__((ext_vector_type(4))) float f32x4;

// ---------------------------------------------------------------------------
// Device-scope grid barrier. Co-residency of all NBLK blocks is guaranteed:
// 512 blocks x 512 thr, __launch_bounds__(512,4) => <=128 VGPR, 19.5KB LDS
// => exactly 2 blocks/CU on 256 CUs. Fresh counter per barrier (no reuse),
// counters zeroed by hipMemsetAsync before launch. Safety valve breaks the
// spin after ~0.5s so a logic bug fails verification instead of hanging.
// ---------------------------------------------------------------------------
__device__ __forceinline__ void grid_sync(unsigned* cnt) {
    __syncthreads();
    if (threadIdx.x == 0) {
        __threadfence();  // agent-scope release of this block's writes
        const unsigned arrived =
            __hip_atomic_fetch_add(cnt, 1u, __ATOMIC_ACQ_REL,
                                   __HIP_MEMORY_SCOPE_AGENT) + 1u;
        if (arrived < NBLK) {
            int spins = 0;
            while (__hip_atomic_load(cnt, __ATOMIC_ACQUIRE,
                                     __HIP_MEMORY_SCOPE_AGENT) < NBLK) {
                __builtin_amdgcn_s_sleep(1);
                if (++spins > (1 << 24)) break;  // fail loud, not hung
            }
        }
        __threadfence();  // agent-scope acquire (invalidate L1/L2)
    }
    __syncthreads();
}

// ---------------------------------------------------------------------------
// Fused attention layer stage (identical math to the verified R7/R8 kernel).
// C/D layout (verified): col=lane&15, row=quad*4+reg.
// ---------------------------------------------------------------------------
template <int HEADS, int D, int DSL, int G, int MW>
__device__ __forceinline__ void attn_stage(
        const int bx, const int by,
        const unsigned* __restrict__ maskT,             // [N/32][N]
        const __hip_bfloat16* __restrict__ WhB,          // [H][N/32][D/16][64][8]
        const float* __restrict__ f1g, const float* __restrict__ f2g,
        float* __restrict__ outp, float* __restrict__ sh,
        float* __restrict__ dsh) {
    constexpr int CTtot = D / 16;
    constexpr int CTT = CTtot / DSL;          // ct-tiles this block owns
    constexpr int CC = (D == 64) ? 1 : 2;     // ct-tiles per epilogue round
    constexpr int KSTEPS = N / (32 * G);
    const int t = threadIdx.x;
    const int g = t >> 6, lane = t & 63;
    const int m = lane & 15, quad = lane >> 4;
    const int h = by / DSL, slc = by % DSL;
    const int i0 = bx * (16 * MW);

    float f1v[MW];
#pragma unroll
    for (int mw = 0; mw < MW; mw++)
        f1v[mw] = f1g[(size_t)h * N + i0 + mw * 16 + m];
    const float* f2p = f2g + (size_t)h * N;
    const bf16x8* whb = (const bf16x8*)WhB + (size_t)h * (N / 32) * CTtot * 64;

    const f32x4 zero = {0.f, 0.f, 0.f, 0.f};
    f32x4 acc[MW][CTT];
    f32x4 sac[MW];
#pragma unroll
    for (int mw = 0; mw < MW; mw++) {
        sac[mw] = zero;
#pragma unroll
        for (int ct = 0; ct < CTT; ct++) acc[mw][ct] = zero;
    }
    const short one_bf = (short)0x3F80;
    const bf16x8 ones = {one_bf, one_bf, one_bf, one_bf,
                         one_bf, one_bf, one_bf, one_bf};

    // -------- K-loop: mask/f2 2-stage pipelined, B-frags single-stage --------
    unsigned mwrd[2][MW];
    float f2v[2][8];
    auto stage_mf = [&](int ks, int b) {
        const int j0 = g * (N / G) + ks * 32;
        const int jw = j0 >> 5;
#pragma unroll
        for (int mw = 0; mw < MW; mw++)
            mwrd[b][mw] = maskT[(size_t)jw * N + i0 + mw * 16 + m];
        const float4 lo = *(const float4*)(f2p + j0 + quad * 8);
        const float4 hi = *(const float4*)(f2p + j0 + quad * 8 + 4);
        f2v[b][0] = lo.x; f2v[b][1] = lo.y; f2v[b][2] = lo.z; f2v[b][3] = lo.w;
        f2v[b][4] = hi.x; f2v[b][5] = hi.y; f2v[b][6] = hi.z; f2v[b][7] = hi.w;
    };

    stage_mf(0, 0);
#pragma unroll 2
    for (int ks = 0; ks < KSTEPS; ks++) {
        const int cur = ks & 1;
        // ---- current-step B frags: issue loads first (hidden under P-gen) ----
        const int jwc = (g * (N / G) + ks * 32) >> 5;
        const bf16x8* bp = whb + ((size_t)jwc * CTtot + slc * CTT) * 64 + lane;
        bf16x8 bfrag[CTT];
#pragma unroll
        for (int ct = 0; ct < CTT; ct++) bfrag[ct] = bp[ct * 64];
        if (ks + 1 < KSTEPS) stage_mf(ks + 1, cur ^ 1);
        // ---- P-gen on current stage ----
        bf16x8 afr[MW];
#pragma unroll
        for (int mw = 0; mw < MW; mw++) {
            const unsigned mword = mwrd[cur][mw] >> (quad * 8);
            float p[8];
#pragma unroll
            for (int e = 0; e < 8; e++) {
                const float tt = f1v[mw] + f2v[cur][e];
                const float lr = fmaxf(tt, 0.5f * tt);        // LeakyReLU(0.5)
                const float pe = __builtin_amdgcn_exp2f(lr);  // log2e folded
                p[e] = ((mword >> e) & 1u) ? pe : 0.f;
            }
            union { bf16x8 v; __hip_bfloat162 h2[4]; } u;
#pragma unroll
            for (int e2 = 0; e2 < 4; e2++)
                u.h2[e2] = __float22bfloat162_rn(
                    make_float2(p[2 * e2], p[2 * e2 + 1]));
            afr[mw] = u.v;
        }
        // ---- MFMAs (B amortized across MW row-tiles) ----
#pragma unroll
        for (int ct = 0; ct < CTT; ct++)
#pragma unroll
            for (int mw = 0; mw < MW; mw++)
                acc[mw][ct] = __builtin_amdgcn_mfma_f32_16x16x32_bf16(
                    afr[mw], bfrag[ct], acc[mw][ct], 0, 0, 0);
#pragma unroll
        for (int mw = 0; mw < MW; mw++)
            sac[mw] = __builtin_amdgcn_mfma_f32_16x16x32_bf16(
                afr[mw], ones, sac[mw], 0, 0, 0);
    }

    // ---- epilogue: LDS cross-group reduction, CC ct-tiles per round ----
#pragma unroll
    for (int rd = 0; rd < CTT / CC; rd++) {
#pragma unroll
        for (int mw = 0; mw < MW; mw++) {
#pragma unroll
            for (int cc = 0; cc < CC; cc++) {
#pragma unroll
                for (int r = 0; r < 4; r++)
                    sh[(((mw * G + g) * 16 + quad * 4 + r) * CC + cc) * 17 + m] =
                        acc[mw][rd * CC + cc][r];
            }
            if (rd == 0 && m == 0) {
#pragma unroll
                for (int r = 0; r < 4; r++)
                    dsh[(mw * G + g) * 16 + quad * 4 + r] = sac[mw][r];
            }
        }
        __syncthreads();
        if (t < 16 * CC * 16) {
            int row, chl;
            if (D == 64) { row = t & 15; chl = (t >> 4) & 15; }
            else         { chl = t & 31; row = (t >> 5) & 15; }
#pragma unroll
            for (int mw = 0; mw < MW; mw++) {
                float av = 0.f, ss = 0.f;
#pragma unroll
                for (int gg = 0; gg < G; gg++) {
                    av += sh[(((mw * G + gg) * 16 + row) * CC + (chl >> 4)) * 17 +
                             (chl & 15)];
                    ss += dsh[(mw * G + gg) * 16 + row];
                }
                float v = av / ss;
                v = (v > 0.f) ? v : (__builtin_amdgcn_exp2f(v * LOG2E) - 1.f);
                const int chg = h * D + slc * (CTT * 16) + rd * CC * 16 + chl;
                const int irow = i0 + mw * 16 + row;
                if (D == 64)
                    outp[(size_t)chg * N + irow] = v;        // h1T[ch][i]
                else
                    outp[(size_t)irow * D + chg] = v;        // out[i][ch]
            }
        }
        __syncthreads();
    }
}

// ---------------------------------------------------------------------------
// Mega-kernel: all four stages in one dispatch, separated by grid barriers.
// 512 blocks x 512 threads = 2 blocks/CU, all co-resident.
//   stage1: gemm1 (t<256) + mask pack (t>=256), per-block row tile i0=bid*8
//   stage2: attn layer 1  (bx=bid&127, by=head=bid>>7)
//   stage3: gemm2 (8 rows/block, 512 thr: rh=t>>7 owns 2 rows)
//   stage4: attn layer 2  (bx=bid&255, by=slice=bid>>8)
// ---------------------------------------------------------------------------
__global__ __launch_bounds__(512, 4) void mega(
        const float* __restrict__ x, const float* __restrict__ W,
        const float* __restrict__ a, const int* __restrict__ adj,
        const float* __restrict__ W2, const float* __restrict__ a2,
        __hip_bfloat16* __restrict__ WhB1, __hip_bfloat16* __restrict__ WhB2,
        float* __restrict__ f1a, float* __restrict__ f2a,
        float* __restrict__ f1b, float* __restrict__ f2b,
        float* __restrict__ h1T, unsigned* __restrict__ maskT,
        float* __restrict__ out, unsigned* __restrict__ bars) {
    __shared__ float shbuf[4608];    // 18 KB: xs / attn sh / hs
    __shared__ float dshbuf[256];    // 1 KB: attn dsh / gemm2 fred
    const int t = threadIdx.x;
    const int bid = blockIdx.x;

    // ================= stage 1: gemm1 + mask pack =================
    {
        const int i0 = bid * 8;
        float4* xs4 = (float4*)shbuf;
        const float4* xg = (const float4*)(x + (size_t)i0 * IN_DIM);
        for (int u = t; u < 8 * IN_DIM / 4; u += 512) xs4[u] = xg[u];
        __syncthreads();
        if (t < 256) {
            // ---- gemm1: x[8 rows] @ W[h] -> WhB1 frag + f1a/f2a ----
            const int c = t & 63, h = t >> 6;
            float acc[8];
#pragma unroll
            for (int r = 0; r < 8; r++) acc[r] = 0.f;
            const float* Wp = W + (size_t)h * IN_DIM * HID + c;
            for (int k = 0; k < IN_DIM; k += 4) {
                const float w0 = Wp[(size_t)(k + 0) * HID];
                const float w1 = Wp[(size_t)(k + 1) * HID];
                const float w2 = Wp[(size_t)(k + 2) * HID];
                const float w3 = Wp[(size_t)(k + 3) * HID];
#pragma unroll
                for (int r = 0; r < 8; r++) {
                    const float4 xv = *(const float4*)(shbuf + r * IN_DIM + k);
                    acc[r] += xv.x * w0 + xv.y * w1 + xv.z * w2 + xv.w * w3;
                }
            }
            union { ushort u[8]; uint4 v; } cv;
#pragma unroll
            for (int r = 0; r < 8; r++)
                cv.u[r] = __hip_bfloat16_raw(__float2bfloat16(acc[r])).x;
            const int jblk = i0 >> 5, quad = (i0 >> 3) & 3;
            const int lane_idx = (c & 15) + 16 * quad;
            *(uint4*)(WhB1 + ((((size_t)h * (N / 32) + jblk) * 4 + (c >> 4)) * 64 +
                              lane_idx) * 8) = cv.v;
            const float av1 = a[h * 2 * HID + c];
            const float av2 = a[h * 2 * HID + HID + c];
            float s1[8], s2[8];
#pragma unroll
            for (int r = 0; r < 8; r++) { s1[r] = acc[r] * av1; s2[r] = acc[r] * av2; }
#pragma unroll
            for (int mm = 32; mm > 0; mm >>= 1) {
#pragma unroll
                for (int r = 0; r < 8; r++) {
                    s1[r] += __shfl_xor(s1[r], mm, 64);
                    s2[r] += __shfl_xor(s2[r], mm, 64);
                }
            }
            if (c == 0) {
#pragma unroll
                for (int r = 0; r < 8; r++) {
                    f1a[(size_t)h * N + i0 + r] = s1[r] * LOG2E;
                    f2a[(size_t)h * N + i0 + r] = s2[r] * LOG2E;
                }
            }
        } else {
            // ---- mask pack (bit-spread, verified R6): waves 4..7, 2 rows each
            const int lane = t & 63, w2 = (t >> 6) - 4;
            for (int r2 = 0; r2 < 2; r2++) {
                const int i = i0 + w2 * 2 + r2;
                const int4* arow = (const int4*)(adj + (size_t)i * N);
                for (int jb = 0; jb < N / 256; jb++) {
                    const int4 a4 = arow[jb * 64 + lane];
                    unsigned long long bal[4];
                    bal[0] = __ballot(a4.x > 0);
                    bal[1] = __ballot(a4.y > 0);
                    bal[2] = __ballot(a4.z > 0);
                    bal[3] = __ballot(a4.w > 0);
                    if (lane < 8) {
                        unsigned word = 0;
#pragma unroll
                        for (int e = 0; e < 4; e++) {
                            unsigned xv = (unsigned)(bal[e] >> (8 * lane)) & 0xFFu;
                            xv = (xv | (xv << 12)) & 0x000F000Fu;
                            xv = (xv | (xv << 6))  & 0x03030303u;
                            xv = (xv | (xv << 3))  & 0x11111111u;
                            word |= xv << e;
                        }
                        maskT[(size_t)(jb * 8 + lane) * N + i] = word;
                    }
                }
            }
        }
    }
    grid_sync(bars + 0);

    // ================= stage 2: attention layer 1 =================
    attn_stage<NHEADS, HID, 1, 8, 2>(bid & 127, bid >> 7, maskT, WhB1,
                                     f1a, f2a, h1T, shbuf, dshbuf);
    grid_sync(bars + 1);

    // ================= stage 3: gemm2 =================
    {
        float* hs = shbuf;
        float* fred = dshbuf;                 // [rh(4)][chalf(2)][rr(2)][fn(2)]
        const int c = t & 127, rh = t >> 7;
        const int i0 = bid * 8;
        for (int u = t; u < 8 * IN_DIM; u += 512) {
            const int r = u & 7, k = u >> 3;
            hs[r * IN_DIM + k] = h1T[(size_t)k * N + i0 + r];
        }
        __syncthreads();
        float acc[2] = {0.f, 0.f};
        for (int k = 0; k < IN_DIM; k += 4) {
            const float w0 = W2[(size_t)(k + 0) * OUT_DIM + c];
            const float w1 = W2[(size_t)(k + 1) * OUT_DIM + c];
            const float w2v = W2[(size_t)(k + 2) * OUT_DIM + c];
            const float w3 = W2[(size_t)(k + 3) * OUT_DIM + c];
#pragma unroll
            for (int rr = 0; rr < 2; rr++) {
                const float4 hv = *(const float4*)(hs + (rh * 2 + rr) * IN_DIM + k);
                acc[rr] += hv.x * w0 + hv.y * w1 + hv.z * w2v + hv.w * w3;
            }
        }
        union { ushort u[2]; unsigned v; } cv;
        cv.u[0] = __hip_bfloat16_raw(__float2bfloat16(acc[0])).x;
        cv.u[1] = __hip_bfloat16_raw(__float2bfloat16(acc[1])).x;
        const int jblk = i0 >> 5, quad = (i0 >> 3) & 3;
        const int lane_idx = (c & 15) + 16 * quad;
        *(unsigned*)((__hip_bfloat16*)WhB2 +
                     (((size_t)jblk * 8 + (c >> 4)) * 64 + lane_idx) * 8 + rh * 2) =
            cv.v;
        const float av1 = a2[c], av2 = a2[OUT_DIM + c];
        float s1[2] = {acc[0] * av1, acc[1] * av1};
        float s2[2] = {acc[0] * av2, acc[1] * av2};
#pragma unroll
        for (int mm = 32; mm > 0; mm >>= 1) {
#pragma unroll
            for (int rr = 0; rr < 2; rr++) {
                s1[rr] += __shfl_xor(s1[rr], mm, 64);
                s2[rr] += __shfl_xor(s2[rr], mm, 64);
            }
        }
        if ((t & 63) == 0) {
            const int chalf = (t >> 6) & 1;
#pragma unroll
            for (int rr = 0; rr < 2; rr++) {
                fred[((rh * 2 + chalf) * 2 + rr) * 2 + 0] = s1[rr];
                fred[((rh * 2 + chalf) * 2 + rr) * 2 + 1] = s2[rr];
            }
        }
        __syncthreads();
        if (t < 16) {
            const int fn = t & 1, rr = (t >> 1) & 1, rh2 = t >> 2;
            const float v = (fred[((rh2 * 2 + 0) * 2 + rr) * 2 + fn] +
                             fred[((rh2 * 2 + 1) * 2 + rr) * 2 + fn]) * LOG2E;
            (fn ? f2b : f1b)[i0 + rh2 * 2 + rr] = v;
        }
    }
    grid_sync(bars + 2);

    // ================= stage 4: attention layer 2 =================
    attn_stage<1, OUT_DIM, 2, 8, 1>(bid & 255, bid >> 8, maskT, WhB2,
                                    f1b, f2b, out, shbuf, dshbuf);
}

// ---------------------------------------------------------------------------
extern "C" void kernel_launch(void* const* d_in, const int* in_sizes, int n_in,
                              void* d_out, int out_size, void* d_ws, size_t ws_size,
                              hipStream_t stream) {
    const float* x   = (const float*)d_in[0];
    const int*   adj = (const int*)d_in[1];
    const float* Wh_ = (const float*)d_in[2];
    const float* ah  = (const float*)d_in[3];
    const float* W2  = (const float*)d_in[4];
    const float* a2  = (const float*)d_in[5];
    float* out = (float*)d_out;

    float* ws = (float*)d_ws;
    float* f1a = ws;                                    // 4*N
    float* f2a = f1a + (size_t)NHEADS * N;              // 4*N
    float* f1b = f2a + (size_t)NHEADS * N;              // N
    float* f2b = f1b + N;                               // N
    float* h1T = f2b + N;                               // 256*N fp32 (4MB)
    __hip_bfloat16* WhB1 = (__hip_bfloat16*)(h1T + (size_t)IN_DIM * N); // 2MB
    __hip_bfloat16* WhB2 = WhB1 + (size_t)NHEADS * HID * N;            // 1MB
    unsigned* maskT = (unsigned*)(WhB2 + (size_t)OUT_DIM * N);         // 2MB
    unsigned* bars = maskT + (size_t)(N / 32) * N;                     // 3 ctrs

    hipMemsetAsync(bars, 0, 3 * sizeof(unsigned), stream);
    mega<<<NBLK, 512, 0, stream>>>(x, Wh_, ah, adj, W2, a2, WhB1, WhB2,
                                   f1a, f2a, f1b, f2b, h1T, maskT, out, bars);
}

// Round 3
// 212.336 us; speedup vs baseline: 2.0550x; 2.0550x over previous
//
#include <hip/hip_runtime.h>
#include <hip/hip_bf16.h>

#define N 4096
#define IN_DIM 256
#define HID 64
#define NHEADS 4
#define OUT_DIM 128
#define LOG2E 1.44269504088896340736f

typedef __attribute__((ext_vector_type(8))) short bf16x8;
typedef __attribute__((ext_vector_type(4))) float f32x4;

// ---------------------------------------------------------------------------
// prep_kernel = gemm1 (blocks 0..511) + mask pack (blocks 512..1535), merged
// so the two independent stages run CONCURRENTLY in one dispatch.
// R3: gemm1 x-reads are wave-uniform -> read x DIRECTLY from global with
// uniform addresses (compiler emits s_load_dwordx4, scalar pipe) instead of
// LDS-broadcast ds_read_b128 which serialized the per-CU LDS pipe (~12cy ea).
// ---------------------------------------------------------------------------
__global__ __launch_bounds__(256, 4) void prep_kernel(
        const float* __restrict__ x, const float* __restrict__ W,
        const float* __restrict__ a, const int* __restrict__ adj,
        __hip_bfloat16* __restrict__ WhB,
        float* __restrict__ f1, float* __restrict__ f2,
        unsigned* __restrict__ maskT) {
    const int t = threadIdx.x;
    if (blockIdx.x < 512) {
        // ---------------- gemm1 ----------------
        const int c = t & 63, h = t >> 6;
        const int i0 = blockIdx.x * 8;
        const float* xb = x + (size_t)i0 * IN_DIM;
        float acc[8];
#pragma unroll
        for (int r = 0; r < 8; r++) acc[r] = 0.f;
        const float* Wp = W + (size_t)h * IN_DIM * HID + c;
#pragma unroll 2
        for (int k = 0; k < IN_DIM; k += 4) {
            const float w0 = Wp[(size_t)(k + 0) * HID];
            const float w1 = Wp[(size_t)(k + 1) * HID];
            const float w2 = Wp[(size_t)(k + 2) * HID];
            const float w3 = Wp[(size_t)(k + 3) * HID];
#pragma unroll
            for (int r = 0; r < 8; r++) {
                // uniform address -> s_load_dwordx4 (scalar pipe, no LDS)
                const float4 xv = *(const float4*)(xb + r * IN_DIM + k);
                acc[r] += xv.x * w0 + xv.y * w1 + xv.z * w2 + xv.w * w3;
            }
        }
        union { ushort u[8]; uint4 v; } cv;
#pragma unroll
        for (int r = 0; r < 8; r++)
            cv.u[r] = __hip_bfloat16_raw(__float2bfloat16(acc[r])).x;
        const int jblk = i0 >> 5, quad = (i0 >> 3) & 3;
        const int lane_idx = (c & 15) + 16 * quad;
        *(uint4*)(WhB + ((((size_t)h * (N / 32) + jblk) * 4 + (c >> 4)) * 64 +
                         lane_idx) * 8) = cv.v;
        const float av1 = a[h * 2 * HID + c];
        const float av2 = a[h * 2 * HID + HID + c];
        float s1[8], s2[8];
#pragma unroll
        for (int r = 0; r < 8; r++) { s1[r] = acc[r] * av1; s2[r] = acc[r] * av2; }
#pragma unroll
        for (int mm = 32; mm > 0; mm >>= 1) {
#pragma unroll
            for (int r = 0; r < 8; r++) {
                s1[r] += __shfl_xor(s1[r], mm, 64);
                s2[r] += __shfl_xor(s2[r], mm, 64);
            }
        }
        if (c == 0) {
#pragma unroll
            for (int r = 0; r < 8; r++) {
                f1[(size_t)h * N + i0 + r] = s1[r] * LOG2E;
                f2[(size_t)h * N + i0 + r] = s2[r] * LOG2E;
            }
        }
    } else {
        // ---------------- mask pack (bit-spread, verified R6) ----------------
        const int lane = t & 63, w = t >> 6;
        const int i = (blockIdx.x - 512) * 4 + w;      // one row per wave
        const int4* arow = (const int4*)(adj + (size_t)i * N);
        for (int jb = 0; jb < N / 256; jb++) {
            const int4 a4 = arow[jb * 64 + lane];
            unsigned long long bal[4];
            bal[0] = __ballot(a4.x > 0);
            bal[1] = __ballot(a4.y > 0);
            bal[2] = __ballot(a4.z > 0);
            bal[3] = __ballot(a4.w > 0);
            if (lane < 8) {
                unsigned word = 0;
#pragma unroll
                for (int e = 0; e < 4; e++) {
                    unsigned xv = (unsigned)(bal[e] >> (8 * lane)) & 0xFFu;
                    xv = (xv | (xv << 12)) & 0x000F000Fu;
                    xv = (xv | (xv << 6))  & 0x03030303u;
                    xv = (xv | (xv << 3))  & 0x11111111u;
                    word |= xv << e;
                }
                maskT[(size_t)(jb * 8 + lane) * N + i] = word;
            }
        }
    }
}

// ---------------------------------------------------------------------------
// Fused attention layer (verified R7/R8 structure).
// L1: HEADS=4, DSL=1, MW=2, G=8 -> grid (128,4)=512 blocks, 512 thr.
// L2: HEADS=1, DSL=1, MW=1, G=8 -> grid (256,1)=256 blocks, 512 thr.
//     (DSL=1 for L2: P computed once instead of twice; CTT=8.)
// C/D layout (verified): col=lane&15, row=quad*4+reg.
// ---------------------------------------------------------------------------
template <int HEADS, int D, int DSL, int G, int MW>
__global__ __launch_bounds__(G * 64, 4) void attn_fused(
        const unsigned* __restrict__ maskT,             // [N/32][N]
        const __hip_bfloat16* __restrict__ WhB,          // [H][N/32][D/16][64][8]
        const float* __restrict__ f1g, const float* __restrict__ f2g,
        float* __restrict__ outp) {
    constexpr int CTtot = D / 16;
    constexpr int CTT = CTtot / DSL;          // ct-tiles this block owns
    constexpr int CC = (D == 64) ? 1 : 2;     // ct-tiles per epilogue round
    constexpr int KSTEPS = N / (32 * G);
    __shared__ float sh[MW * G * 16 * CC * 17];
    __shared__ float dsh[MW * G * 16];
    const int t = threadIdx.x;
    const int g = t >> 6, lane = t & 63;
    const int m = lane & 15, quad = lane >> 4;
    const int h = blockIdx.y / DSL, slc = blockIdx.y % DSL;
    const int i0 = blockIdx.x * (16 * MW);

    float f1v[MW];
#pragma unroll
    for (int mw = 0; mw < MW; mw++)
        f1v[mw] = f1g[(size_t)h * N + i0 + mw * 16 + m];
    const float* f2p = f2g + (size_t)h * N;
    const bf16x8* whb = (const bf16x8*)WhB + (size_t)h * (N / 32) * CTtot * 64;

    const f32x4 zero = {0.f, 0.f, 0.f, 0.f};
    f32x4 acc[MW][CTT];
    f32x4 sac[MW];
#pragma unroll
    for (int mw = 0; mw < MW; mw++) {
        sac[mw] = zero;
#pragma unroll
        for (int ct = 0; ct < CTT; ct++) acc[mw][ct] = zero;
    }
    const short one_bf = (short)0x3F80;
    const bf16x8 ones = {one_bf, one_bf, one_bf, one_bf,
                         one_bf, one_bf, one_bf, one_bf};

    // -------- K-loop: mask/f2 2-stage pipelined, B-frags single-stage --------
    unsigned mwrd[2][MW];
    float f2v[2][8];
    auto stage_mf = [&](int ks, int b) {
        const int j0 = g * (N / G) + ks * 32;
        const int jw = j0 >> 5;
#pragma unroll
        for (int mw = 0; mw < MW; mw++)
            mwrd[b][mw] = maskT[(size_t)jw * N + i0 + mw * 16 + m];
        const float4 lo = *(const float4*)(f2p + j0 + quad * 8);
        const float4 hi = *(const float4*)(f2p + j0 + quad * 8 + 4);
        f2v[b][0] = lo.x; f2v[b][1] = lo.y; f2v[b][2] = lo.z; f2v[b][3] = lo.w;
        f2v[b][4] = hi.x; f2v[b][5] = hi.y; f2v[b][6] = hi.z; f2v[b][7] = hi.w;
    };

    stage_mf(0, 0);
#pragma unroll 2
    for (int ks = 0; ks < KSTEPS; ks++) {
        const int cur = ks & 1;
        // ---- current-step B frags: issue loads first (hidden under P-gen) ----
        const int jwc = (g * (N / G) + ks * 32) >> 5;
        const bf16x8* bp = whb + ((size_t)jwc * CTtot + slc * CTT) * 64 + lane;
        bf16x8 bfrag[CTT];
#pragma unroll
        for (int ct = 0; ct < CTT; ct++) bfrag[ct] = bp[ct * 64];
        if (ks + 1 < KSTEPS) stage_mf(ks + 1, cur ^ 1);
        // ---- P-gen on current stage ----
        bf16x8 afr[MW];
#pragma unroll
        for (int mw = 0; mw < MW; mw++) {
            const unsigned mword = mwrd[cur][mw] >> (quad * 8);
            float p[8];
#pragma unroll
            for (int e = 0; e < 8; e++) {
                const float tt = f1v[mw] + f2v[cur][e];
                const float lr = fmaxf(tt, 0.5f * tt);        // LeakyReLU(0.5)
                const float pe = __builtin_amdgcn_exp2f(lr);  // log2e folded
                p[e] = ((mword >> e) & 1u) ? pe : 0.f;
            }
            union { bf16x8 v; __hip_bfloat162 h2[4]; } u;
#pragma unroll
            for (int e2 = 0; e2 < 4; e2++)
                u.h2[e2] = __float22bfloat162_rn(
                    make_float2(p[2 * e2], p[2 * e2 + 1]));
            afr[mw] = u.v;
        }
        // ---- MFMAs (B amortized across MW row-tiles) ----
#pragma unroll
        for (int ct = 0; ct < CTT; ct++)
#pragma unroll
            for (int mw = 0; mw < MW; mw++)
                acc[mw][ct] = __builtin_amdgcn_mfma_f32_16x16x32_bf16(
                    afr[mw], bfrag[ct], acc[mw][ct], 0, 0, 0);
#pragma unroll
        for (int mw = 0; mw < MW; mw++)
            sac[mw] = __builtin_amdgcn_mfma_f32_16x16x32_bf16(
                afr[mw], ones, sac[mw], 0, 0, 0);
    }

    // ---- epilogue: LDS cross-group reduction, CC ct-tiles per round ----
#pragma unroll
    for (int rd = 0; rd < CTT / CC; rd++) {
#pragma unroll
        for (int mw = 0; mw < MW; mw++) {
#pragma unroll
            for (int cc = 0; cc < CC; cc++) {
#pragma unroll
                for (int r = 0; r < 4; r++)
                    sh[(((mw * G + g) * 16 + quad * 4 + r) * CC + cc) * 17 + m] =
                        acc[mw][rd * CC + cc][r];
            }
            if (rd == 0 && m == 0) {
#pragma unroll
                for (int r = 0; r < 4; r++)
                    dsh[(mw * G + g) * 16 + quad * 4 + r] = sac[mw][r];
            }
        }
        __syncthreads();
        if (t < 16 * CC * 16) {
            int row, chl;
            if (D == 64) { row = t & 15; chl = (t >> 4) & 15; }
            else         { chl = t & 31; row = (t >> 5) & 15; }
#pragma unroll
            for (int mw = 0; mw < MW; mw++) {
                float av = 0.f, ss = 0.f;
#pragma unroll
                for (int gg = 0; gg < G; gg++) {
                    av += sh[(((mw * G + gg) * 16 + row) * CC + (chl >> 4)) * 17 +
                             (chl & 15)];
                    ss += dsh[(mw * G + gg) * 16 + row];
                }
                float v = av / ss;
                v = (v > 0.f) ? v : (__builtin_amdgcn_exp2f(v * LOG2E) - 1.f);
                const int chg = h * D + slc * (CTT * 16) + rd * CC * 16 + chl;
                const int irow = i0 + mw * 16 + row;
                if (D == 64)
                    outp[(size_t)chg * N + irow] = v;        // h1T[ch][i]
                else
                    outp[(size_t)irow * D + chg] = v;        // out[i][ch]
            }
        }
        __syncthreads();
    }
}

// ---------------------------------------------------------------------------
// gemm2: h1T[256][N] (k-major) @ W_out[256][128] -> WhB2 fragment bf16
// [j/32][ct(8)][lane][e] + fused f1b/f2b.
// R3: h1T reads are wave-uniform -> uniform global loads (s_load_dwordx4 of
// h1T[k][i0+rh*4..+3], contiguous in rows) instead of LDS staging+broadcast.
// ---------------------------------------------------------------------------
__global__ __launch_bounds__(256, 4) void gemm2_kernel(
        const float* __restrict__ h1T, const float* __restrict__ W2,
        const float* __restrict__ a2, __hip_bfloat16* __restrict__ WhB2,
        float* __restrict__ f1, float* __restrict__ f2) {
    __shared__ float fred[2][2][4][2];   // [rh][chalf][r][fn]
    const int t = threadIdx.x;
    const int c = t & 127, rh = t >> 7;
    const int i0 = blockIdx.x * 8;
    const float* hb = h1T + i0 + rh * 4;
    const float* w2p = W2 + c;
    float acc[4];
#pragma unroll
    for (int rr = 0; rr < 4; rr++) acc[rr] = 0.f;
#pragma unroll 4
    for (int k = 0; k < IN_DIM; k++) {
        // uniform address -> s_load_dwordx4 (rows rh*4..rh*4+3 of column k)
        const float4 hv = *(const float4*)(hb + (size_t)k * N);
        const float wv = w2p[(size_t)k * OUT_DIM];
        acc[0] += hv.x * wv; acc[1] += hv.y * wv;
        acc[2] += hv.z * wv; acc[3] += hv.w * wv;
    }
    union { ushort u[4]; uint2 v; } cv;
#pragma unroll
    for (int rr = 0; rr < 4; rr++)
        cv.u[rr] = __hip_bfloat16_raw(__float2bfloat16(acc[rr])).x;
    const int jblk = i0 >> 5, quad = (i0 >> 3) & 3;
    const int lane_idx = (c & 15) + 16 * quad;
    *(uint2*)((__hip_bfloat16*)WhB2 +
              (((size_t)jblk * 8 + (c >> 4)) * 64 + lane_idx) * 8 + rh * 4) = cv.v;
    const float av1 = a2[c], av2 = a2[OUT_DIM + c];
    float s1[4], s2[4];
#pragma unroll
    for (int rr = 0; rr < 4; rr++) { s1[rr] = acc[rr] * av1; s2[rr] = acc[rr] * av2; }
#pragma unroll
    for (int mm = 32; mm > 0; mm >>= 1) {
#pragma unroll
        for (int rr = 0; rr < 4; rr++) {
            s1[rr] += __shfl_xor(s1[rr], mm, 64);
            s2[rr] += __shfl_xor(s2[rr], mm, 64);
        }
    }
    if ((t & 63) == 0) {
        const int chalf = (t >> 6) & 1;
#pragma unroll
        for (int rr = 0; rr < 4; rr++) {
            fred[rh][chalf][rr][0] = s1[rr];
            fred[rh][chalf][rr][1] = s2[rr];
        }
    }
    __syncthreads();
    if (t < 16) {
        const int fn = t & 1, rr = (t >> 1) & 3, rh2 = t >> 3;
        const float v = (fred[rh2][0][rr][fn] + fred[rh2][1][rr][fn]) * LOG2E;
        (fn ? f2 : f1)[i0 + rh2 * 4 + rr] = v;
    }
}

// ---------------------------------------------------------------------------
extern "C" void kernel_launch(void* const* d_in, const int* in_sizes, int n_in,
                              void* d_out, int out_size, void* d_ws, size_t ws_size,
                              hipStream_t stream) {
    const float* x   = (const float*)d_in[0];
    const int*   adj = (const int*)d_in[1];
    const float* Wh_ = (const float*)d_in[2];
    const float* ah  = (const float*)d_in[3];
    const float* W2  = (const float*)d_in[4];
    const float* a2  = (const float*)d_in[5];
    float* out = (float*)d_out;

    float* ws = (float*)d_ws;
    float* f1a = ws;                                    // 4*N
    float* f2a = f1a + (size_t)NHEADS * N;              // 4*N
    float* f1b = f2a + (size_t)NHEADS * N;              // N
    float* f2b = f1b + N;                               // N
    float* h1T = f2b + N;                               // 256*N fp32 (4MB)
    __hip_bfloat16* WhB1 = (__hip_bfloat16*)(h1T + (size_t)IN_DIM * N); // 2MB
    __hip_bfloat16* WhB2 = WhB1 + (size_t)NHEADS * HID * N;            // 1MB
    unsigned* maskT = (unsigned*)(WhB2 + (size_t)OUT_DIM * N);         // 2MB

    // gemm1 (blocks 0..511) + mask pack (512..1535), concurrent
    prep_kernel<<<1536, 256, 0, stream>>>(x, Wh_, ah, adj, WhB1, f1a, f2a, maskT);
    attn_fused<NHEADS, HID, 1, 8, 2>
        <<<dim3(N / 32, NHEADS), 512, 0, stream>>>(maskT, WhB1, f1a, f2a, h1T);
    gemm2_kernel<<<N / 8, 256, 0, stream>>>(h1T, W2, a2, WhB2, f1b, f2b);
    attn_fused<1, OUT_DIM, 1, 8, 1>
        <<<dim3(N / 16, 1), 512, 0, stream>>>(maskT, WhB2, f1b, f2b, out);
}

// Round 5
// 169.189 us; speedup vs baseline: 2.5791x; 1.2550x over previous
//
#include <hip/hip_runtime.h>
#include <hip/hip_bf16.h>

#define N 4096
#define IN_DIM 256
#define HID 64
#define NHEADS 4
#define OUT_DIM 128
#define LOG2E 1.44269504088896340736f

typedef __attribute__((ext_vector_type(8))) short bf16x8;
typedef __attribute__((ext_vector_type(4))) float f32x4;

// Two-term bf16 split: v ~= hi + lo with |err| ~ 2^-17 |v|.
// Returned by value (ushort2) because refs can't bind to vector elements.
__device__ __forceinline__ ushort2 bsplit(float v) {
    const ushort h = __hip_bfloat16_raw(__float2bfloat16(v)).x;
    const float vh = __uint_as_float((unsigned)h << 16);
    const ushort l = __hip_bfloat16_raw(__float2bfloat16(v - vh)).x;
    return make_ushort2(h, l);
}

// ---------------------------------------------------------------------------
// prep_kernel = gemm1-MFMA (blocks 0..255) + mask pack (blocks 256..1279).
// gemm1 via mfma_f32_16x16x32_bf16 with bf16 hi/lo split (3 MFMAs per tile,
// err ~1e-5): block = 16 rows, wave w = head w, 4 ct-tiles of 16 cols.
// Frag layouts (verified against attn producer/consumer pair):
//   A[row=lane&15][k=quad*8+e], B[k=quad*8+e][col=lane&15],
//   C[row=quad*4+r][col=lane&15].
// ---------------------------------------------------------------------------
__global__ __launch_bounds__(256, 4) void prep_kernel(
        const float* __restrict__ x, const float* __restrict__ W,
        const float* __restrict__ a, const int* __restrict__ adj,
        __hip_bfloat16* __restrict__ WhB,
        float* __restrict__ f1, float* __restrict__ f2,
        unsigned* __restrict__ maskT) {
    const int t = threadIdx.x;
    if (blockIdx.x < 256) {
        // ---------------- gemm1 via MFMA ----------------
        const int h = t >> 6, lane = t & 63, m = lane & 15, quad = lane >> 4;
        const int i0 = blockIdx.x * 16;
        const float* xrow = x + (size_t)(i0 + m) * IN_DIM;
        const float* Wp = W + (size_t)h * IN_DIM * HID;
        const f32x4 zero = {0.f, 0.f, 0.f, 0.f};
        f32x4 acc[4] = {zero, zero, zero, zero};
        for (int ks = 0; ks < 8; ks++) {
            const int kb = ks * 32 + quad * 8;
            const float4 xa = *(const float4*)(xrow + kb);
            const float4 xb = *(const float4*)(xrow + kb + 4);
            const float xf[8] = {xa.x, xa.y, xa.z, xa.w, xb.x, xb.y, xb.z, xb.w};
            bf16x8 xh, xl;
#pragma unroll
            for (int e = 0; e < 8; e++) {
                const ushort2 s = bsplit(xf[e]);
                xh[e] = (short)s.x; xl[e] = (short)s.y;
            }
#pragma unroll
            for (int ct = 0; ct < 4; ct++) {
                bf16x8 wh, wl;
#pragma unroll
                for (int e = 0; e < 8; e++) {
                    const ushort2 s =
                        bsplit(Wp[(size_t)(kb + e) * HID + ct * 16 + m]);
                    wh[e] = (short)s.x; wl[e] = (short)s.y;
                }
                acc[ct] = __builtin_amdgcn_mfma_f32_16x16x32_bf16(
                    xh, wh, acc[ct], 0, 0, 0);
                acc[ct] = __builtin_amdgcn_mfma_f32_16x16x32_bf16(
                    xl, wh, acc[ct], 0, 0, 0);
                acc[ct] = __builtin_amdgcn_mfma_f32_16x16x32_bf16(
                    xh, wl, acc[ct], 0, 0, 0);
            }
        }
        // ---- WhB1 frag store: j = i0+quad*4+r, c = ct*16+m ----
        const int jblk = i0 >> 5, jb2 = (i0 >> 4) & 1;
#pragma unroll
        for (int ct = 0; ct < 4; ct++) {
#pragma unroll
            for (int r = 0; r < 4; r++) {
                const int jo = quad * 4 + r;
                const int lane_idx = m + 16 * (2 * jb2 + (jo >> 3));
                WhB[((((size_t)h * (N / 32) + jblk) * 4 + ct) * 64 + lane_idx) *
                        8 + (jo & 7)] = __float2bfloat16(acc[ct][r]);
            }
        }
        // ---- f1/f2: s = sum_c Wh[i][c]*a[c], reduce over m within quad ----
        float av1[4], av2[4];
#pragma unroll
        for (int ct = 0; ct < 4; ct++) {
            av1[ct] = a[h * 2 * HID + ct * 16 + m];
            av2[ct] = a[h * 2 * HID + HID + ct * 16 + m];
        }
        float s1[4], s2[4];
#pragma unroll
        for (int r = 0; r < 4; r++) {
            s1[r] = 0.f; s2[r] = 0.f;
#pragma unroll
            for (int ct = 0; ct < 4; ct++) {
                s1[r] += acc[ct][r] * av1[ct];
                s2[r] += acc[ct][r] * av2[ct];
            }
        }
#pragma unroll
        for (int mm = 8; mm > 0; mm >>= 1) {
#pragma unroll
            for (int r = 0; r < 4; r++) {
                s1[r] += __shfl_xor(s1[r], mm, 64);
                s2[r] += __shfl_xor(s2[r], mm, 64);
            }
        }
        if (m == 0) {
#pragma unroll
            for (int r = 0; r < 4; r++) {
                f1[(size_t)h * N + i0 + quad * 4 + r] = s1[r] * LOG2E;
                f2[(size_t)h * N + i0 + quad * 4 + r] = s2[r] * LOG2E;
            }
        }
    } else {
        // ---------------- mask pack (bit-spread, verified R6) ----------------
        const int lane = t & 63, w = t >> 6;
        const int i = (blockIdx.x - 256) * 4 + w;      // one row per wave
        const int4* arow = (const int4*)(adj + (size_t)i * N);
        for (int jb = 0; jb < N / 256; jb++) {
            const int4 a4 = arow[jb * 64 + lane];
            unsigned long long bal[4];
            bal[0] = __ballot(a4.x > 0);
            bal[1] = __ballot(a4.y > 0);
            bal[2] = __ballot(a4.z > 0);
            bal[3] = __ballot(a4.w > 0);
            if (lane < 8) {
                unsigned word = 0;
#pragma unroll
                for (int e = 0; e < 4; e++) {
                    unsigned xv = (unsigned)(bal[e] >> (8 * lane)) & 0xFFu;
                    xv = (xv | (xv << 12)) & 0x000F000Fu;
                    xv = (xv | (xv << 6))  & 0x03030303u;
                    xv = (xv | (xv << 3))  & 0x11111111u;
                    word |= xv << e;
                }
                maskT[(size_t)(jb * 8 + lane) * N + i] = word;
            }
        }
    }
}

// ---------------------------------------------------------------------------
// Fused attention layer (verified R7/R8 structure; R5: D==64 output goes
// ROW-major h1[i][256] so gemm2's MFMA A-frags are contiguous).
// L1: HEADS=4, DSL=1, MW=2, G=8 -> grid (128,4)=512 blocks, 512 thr.
// L2: HEADS=1, DSL=2, MW=1, G=8 -> grid (256,2)=512 blocks, 512 thr.
// C/D layout (verified): col=lane&15, row=quad*4+reg.
// ---------------------------------------------------------------------------
template <int HEADS, int D, int DSL, int G, int MW>
__global__ __launch_bounds__(G * 64, 4) void attn_fused(
        const unsigned* __restrict__ maskT,             // [N/32][N]
        const __hip_bfloat16* __restrict__ WhB,          // [H][N/32][D/16][64][8]
        const float* __restrict__ f1g, const float* __restrict__ f2g,
        float* __restrict__ outp) {
    constexpr int CTtot = D / 16;
    constexpr int CTT = CTtot / DSL;          // ct-tiles this block owns
    constexpr int CC = (D == 64) ? 1 : 2;     // ct-tiles per epilogue round
    constexpr int KSTEPS = N / (32 * G);
    __shared__ float sh[MW * G * 16 * CC * 17];
    __shared__ float dsh[MW * G * 16];
    const int t = threadIdx.x;
    const int g = t >> 6, lane = t & 63;
    const int m = lane & 15, quad = lane >> 4;
    const int h = blockIdx.y / DSL, slc = blockIdx.y % DSL;
    const int i0 = blockIdx.x * (16 * MW);

    float f1v[MW];
#pragma unroll
    for (int mw = 0; mw < MW; mw++)
        f1v[mw] = f1g[(size_t)h * N + i0 + mw * 16 + m];
    const float* f2p = f2g + (size_t)h * N;
    const bf16x8* whb = (const bf16x8*)WhB + (size_t)h * (N / 32) * CTtot * 64;

    const f32x4 zero = {0.f, 0.f, 0.f, 0.f};
    f32x4 acc[MW][CTT];
    f32x4 sac[MW];
#pragma unroll
    for (int mw = 0; mw < MW; mw++) {
        sac[mw] = zero;
#pragma unroll
        for (int ct = 0; ct < CTT; ct++) acc[mw][ct] = zero;
    }
    const short one_bf = (short)0x3F80;
    const bf16x8 ones = {one_bf, one_bf, one_bf, one_bf,
                         one_bf, one_bf, one_bf, one_bf};

    // -------- K-loop: mask/f2 2-stage pipelined, B-frags single-stage --------
    unsigned mwrd[2][MW];
    float f2v[2][8];
    auto stage_mf = [&](int ks, int b) {
        const int j0 = g * (N / G) + ks * 32;
        const int jw = j0 >> 5;
#pragma unroll
        for (int mw = 0; mw < MW; mw++)
            mwrd[b][mw] = maskT[(size_t)jw * N + i0 + mw * 16 + m];
        const float4 lo = *(const float4*)(f2p + j0 + quad * 8);
        const float4 hi = *(const float4*)(f2p + j0 + quad * 8 + 4);
        f2v[b][0] = lo.x; f2v[b][1] = lo.y; f2v[b][2] = lo.z; f2v[b][3] = lo.w;
        f2v[b][4] = hi.x; f2v[b][5] = hi.y; f2v[b][6] = hi.z; f2v[b][7] = hi.w;
    };

    stage_mf(0, 0);
#pragma unroll 2
    for (int ks = 0; ks < KSTEPS; ks++) {
        const int cur = ks & 1;
        // ---- current-step B frags: issue loads first (hidden under P-gen) ----
        const int jwc = (g * (N / G) + ks * 32) >> 5;
        const bf16x8* bp = whb + ((size_t)jwc * CTtot + slc * CTT) * 64 + lane;
        bf16x8 bfrag[CTT];
#pragma unroll
        for (int ct = 0; ct < CTT; ct++) bfrag[ct] = bp[ct * 64];
        if (ks + 1 < KSTEPS) stage_mf(ks + 1, cur ^ 1);
        // ---- P-gen on current stage ----
        bf16x8 afr[MW];
#pragma unroll
        for (int mw = 0; mw < MW; mw++) {
            const unsigned mword = mwrd[cur][mw] >> (quad * 8);
            float p[8];
#pragma unroll
            for (int e = 0; e < 8; e++) {
                const float tt = f1v[mw] + f2v[cur][e];
                const float lr = fmaxf(tt, 0.5f * tt);        // LeakyReLU(0.5)
                const float pe = __builtin_amdgcn_exp2f(lr);  // log2e folded
                p[e] = ((mword >> e) & 1u) ? pe : 0.f;
            }
            union { bf16x8 v; __hip_bfloat162 h2[4]; } u;
#pragma unroll
            for (int e2 = 0; e2 < 4; e2++)
                u.h2[e2] = __float22bfloat162_rn(
                    make_float2(p[2 * e2], p[2 * e2 + 1]));
            afr[mw] = u.v;
        }
        // ---- MFMAs (B amortized across MW row-tiles) ----
#pragma unroll
        for (int ct = 0; ct < CTT; ct++)
#pragma unroll
            for (int mw = 0; mw < MW; mw++)
                acc[mw][ct] = __builtin_amdgcn_mfma_f32_16x16x32_bf16(
                    afr[mw], bfrag[ct], acc[mw][ct], 0, 0, 0);
#pragma unroll
        for (int mw = 0; mw < MW; mw++)
            sac[mw] = __builtin_amdgcn_mfma_f32_16x16x32_bf16(
                afr[mw], ones, sac[mw], 0, 0, 0);
    }

    // ---- epilogue: LDS cross-group reduction, CC ct-tiles per round ----
#pragma unroll
    for (int rd = 0; rd < CTT / CC; rd++) {
#pragma unroll
        for (int mw = 0; mw < MW; mw++) {
#pragma unroll
            for (int cc = 0; cc < CC; cc++) {
#pragma unroll
                for (int r = 0; r < 4; r++)
                    sh[(((mw * G + g) * 16 + quad * 4 + r) * CC + cc) * 17 + m] =
                        acc[mw][rd * CC + cc][r];
            }
            if (rd == 0 && m == 0) {
#pragma unroll
                for (int r = 0; r < 4; r++)
                    dsh[(mw * G + g) * 16 + quad * 4 + r] = sac[mw][r];
            }
        }
        __syncthreads();
        if (t < 16 * CC * 16) {
            int row, chl;
            if (D == 64) { row = t & 15; chl = (t >> 4) & 15; }
            else         { chl = t & 31; row = (t >> 5) & 15; }
#pragma unroll
            for (int mw = 0; mw < MW; mw++) {
                float av = 0.f, ss = 0.f;
#pragma unroll
                for (int gg = 0; gg < G; gg++) {
                    av += sh[(((mw * G + gg) * 16 + row) * CC + (chl >> 4)) * 17 +
                             (chl & 15)];
                    ss += dsh[(mw * G + gg) * 16 + row];
                }
                float v = av / ss;
                v = (v > 0.f) ? v : (__builtin_amdgcn_exp2f(v * LOG2E) - 1.f);
                const int chg = h * D + slc * (CTT * 16) + rd * CC * 16 + chl;
                const int irow = i0 + mw * 16 + row;
                if (D == 64)
                    outp[(size_t)irow * (NHEADS * HID) + chg] = v;  // h1[i][ch]
                else
                    outp[(size_t)irow * D + chg] = v;               // out[i][ch]
            }
        }
        __syncthreads();
    }
}

// ---------------------------------------------------------------------------
// gemm2 via MFMA bf16-split: h1[4096][256] @ W2[256][128].
// Block = 16 rows, 8 waves; wave w owns ct-tile w (cols w*16..w*16+15).
// Outputs WhB2 frag layout [j/32][ct(8)][64][8] + f1b/f2b (LDS cross-wave).
// ---------------------------------------------------------------------------
__global__ __launch_bounds__(512, 2) void gemm2_kernel(
        const float* __restrict__ h1, const float* __restrict__ W2,
        const float* __restrict__ a2, __hip_bfloat16* __restrict__ WhB2,
        float* __restrict__ f1, float* __restrict__ f2) {
    __shared__ float fred[8][16][2];
    const int t = threadIdx.x;
    const int w = t >> 6, lane = t & 63, m = lane & 15, quad = lane >> 4;
    const int i0 = blockIdx.x * 16;
    const float* arow = h1 + (size_t)(i0 + m) * IN_DIM;
    const float* wp = W2 + w * 16 + m;
    const f32x4 zero = {0.f, 0.f, 0.f, 0.f};
    f32x4 acc = zero;
    for (int ks = 0; ks < 8; ks++) {
        const int kb = ks * 32 + quad * 8;
        const float4 xa = *(const float4*)(arow + kb);
        const float4 xb = *(const float4*)(arow + kb + 4);
        const float xf[8] = {xa.x, xa.y, xa.z, xa.w, xb.x, xb.y, xb.z, xb.w};
        bf16x8 xh, xl, wh, wl;
#pragma unroll
        for (int e = 0; e < 8; e++) {
            const ushort2 s = bsplit(xf[e]);
            xh[e] = (short)s.x; xl[e] = (short)s.y;
        }
#pragma unroll
        for (int e = 0; e < 8; e++) {
            const ushort2 s = bsplit(wp[(size_t)(kb + e) * OUT_DIM]);
            wh[e] = (short)s.x; wl[e] = (short)s.y;
        }
        acc = __builtin_amdgcn_mfma_f32_16x16x32_bf16(xh, wh, acc, 0, 0, 0);
        acc = __builtin_amdgcn_mfma_f32_16x16x32_bf16(xl, wh, acc, 0, 0, 0);
        acc = __builtin_amdgcn_mfma_f32_16x16x32_bf16(xh, wl, acc, 0, 0, 0);
    }
    // ---- WhB2 frag store: j = i0+quad*4+r, c = w*16+m ----
    const int jblk = i0 >> 5, jb2 = (i0 >> 4) & 1;
#pragma unroll
    for (int r = 0; r < 4; r++) {
        const int jo = quad * 4 + r;
        const int lane_idx = m + 16 * (2 * jb2 + (jo >> 3));
        WhB2[(((size_t)jblk * 8 + w) * 64 + lane_idx) * 8 + (jo & 7)] =
            __float2bfloat16(acc[r]);
    }
    // ---- f1b/f2b: reduce over m (shfl) then over waves (LDS) ----
    const float av1 = a2[w * 16 + m], av2 = a2[OUT_DIM + w * 16 + m];
    float s1[4], s2[4];
#pragma unroll
    for (int r = 0; r < 4; r++) { s1[r] = acc[r] * av1; s2[r] = acc[r] * av2; }
#pragma unroll
    for (int mm = 8; mm > 0; mm >>= 1) {
#pragma unroll
        for (int r = 0; r < 4; r++) {
            s1[r] += __shfl_xor(s1[r], mm, 64);
            s2[r] += __shfl_xor(s2[r], mm, 64);
        }
    }
    if (m == 0) {
#pragma unroll
        for (int r = 0; r < 4; r++) {
            fred[w][quad * 4 + r][0] = s1[r];
            fred[w][quad * 4 + r][1] = s2[r];
        }
    }
    __syncthreads();
    if (t < 32) {
        const int row = t & 15, fn = t >> 4;
        float s = 0.f;
#pragma unroll
        for (int w8 = 0; w8 < 8; w8++) s += fred[w8][row][fn];
        (fn ? f2 : f1)[i0 + row] = s * LOG2E;
    }
}

// ---------------------------------------------------------------------------
extern "C" void kernel_launch(void* const* d_in, const int* in_sizes, int n_in,
                              void* d_out, int out_size, void* d_ws, size_t ws_size,
                              hipStream_t stream) {
    const float* x   = (const float*)d_in[0];
    const int*   adj = (const int*)d_in[1];
    const float* Wh_ = (const float*)d_in[2];
    const float* ah  = (const float*)d_in[3];
    const float* W2  = (const float*)d_in[4];
    const float* a2  = (const float*)d_in[5];
    float* out = (float*)d_out;

    float* ws = (float*)d_ws;
    float* f1a = ws;                                    // 4*N
    float* f2a = f1a + (size_t)NHEADS * N;              // 4*N
    float* f1b = f2a + (size_t)NHEADS * N;              // N
    float* f2b = f1b + N;                               // N
    float* h1  = f2b + N;                               // N*256 fp32 (4MB)
    __hip_bfloat16* WhB1 = (__hip_bfloat16*)(h1 + (size_t)IN_DIM * N);  // 2MB
    __hip_bfloat16* WhB2 = WhB1 + (size_t)NHEADS * HID * N;            // 1MB
    unsigned* maskT = (unsigned*)(WhB2 + (size_t)OUT_DIM * N);         // 2MB

    // gemm1-MFMA (blocks 0..255) + mask pack (256..1279), concurrent
    prep_kernel<<<1280, 256, 0, stream>>>(x, Wh_, ah, adj, WhB1, f1a, f2a, maskT);
    attn_fused<NHEADS, HID, 1, 8, 2>
        <<<dim3(N / 32, NHEADS), 512, 0, stream>>>(maskT, WhB1, f1a, f2a, h1);
    gemm2_kernel<<<N / 16, 512, 0, stream>>>(h1, W2, a2, WhB2, f1b, f2b);
    attn_fused<1, OUT_DIM, 2, 8, 1>
        <<<dim3(N / 16, 2), 512, 0, stream>>>(maskT, WhB2, f1b, f2b, out);
}